// Round 5
// baseline (498.011 us; speedup 1.0000x reference)
//
#include <hip/hip_runtime.h>
#include <hip/hip_bf16.h>
#include <math.h>

#define DIMD   1024
#define NBATCH 4
#define NSEQ   8192
#define NTOK   (NBATCH * NSEQ)
#define NHEAVY 1024
#define NSEL   (NBATCH * NHEAVY)
#define DLIGHT 512
#define DHEAVY 4096
#define NITERS 50

typedef __attribute__((ext_vector_type(8))) short short8;
typedef __attribute__((ext_vector_type(4))) float f32x4;

__device__ __forceinline__ float gelu_exact(float x) {
    return 0.5f * x * (1.0f + erff(x * 0.7071067811865475f));
}

__device__ __forceinline__ void gload_lds16(const void* g, void* l) {
    __builtin_amdgcn_global_load_lds(
        (const __attribute__((address_space(1))) void*)g,
        (__attribute__((address_space(3))) void*)l,
        16, 0, 0);
}

// in[K][N] f32  ->  out[N][K] bf16   (transpose + convert)
__global__ void cvt_transpose(const float* __restrict__ in, __hip_bfloat16* __restrict__ out,
                              int K, int N) {
    __shared__ float tile[32][33];
    int n0 = blockIdx.x * 32, k0 = blockIdx.y * 32;
    int tx = threadIdx.x, ty = threadIdx.y;  // (32, 8)
    #pragma unroll
    for (int j = 0; j < 4; j++)
        tile[ty + 8 * j][tx] = in[(size_t)(k0 + ty + 8 * j) * N + (n0 + tx)];
    __syncthreads();
    #pragma unroll
    for (int j = 0; j < 4; j++)
        out[(size_t)(n0 + ty + 8 * j) * K + (k0 + tx)] = __float2bfloat16(tile[tx][ty + 8 * j]);
}

// rmsnorm (fp32) -> bf16. GATHER: token row from sel list.
// WITH_S: also computes s[token] = dot(x_row, rt) in f64 (fused router dot).
template <bool GATHER, bool WITH_S>
__global__ void rmsnorm_kern(const float* __restrict__ x, const float* __restrict__ gamma,
                             const int* __restrict__ rows, __hip_bfloat16* __restrict__ out,
                             int tok0, const float* __restrict__ rt, double* __restrict__ s_out) {
    int t = blockIdx.x;
    int grow = GATHER ? rows[t] : (tok0 + t);
    const float4* xr = (const float4*)(x + (size_t)grow * DIMD);
    int tid = threadIdx.x;  // 256
    float4 v = xr[tid];
    float ss = v.x * v.x + v.y * v.y + v.z * v.z + v.w * v.w;
    double sd = 0.0;
    if (WITH_S) {
        float4 rv = ((const float4*)rt)[tid];
        sd = (double)v.x * rv.x + (double)v.y * rv.y + (double)v.z * rv.z + (double)v.w * rv.w;
    }
    #pragma unroll
    for (int off = 32; off > 0; off >>= 1) {
        ss += __shfl_down(ss, off);
        if (WITH_S) sd += __shfl_down(sd, off);
    }
    __shared__ float red[4];
    __shared__ double redd[4];
    if ((tid & 63) == 0) { red[tid >> 6] = ss; if (WITH_S) redd[tid >> 6] = sd; }
    __syncthreads();
    float tot = red[0] + red[1] + red[2] + red[3];
    if (WITH_S && tid == 0) s_out[grow] = redd[0] + redd[1] + redd[2] + redd[3];
    float sc = 32.0f / fmaxf(sqrtf(tot), 1e-12f);  // sqrt(1024)=32
    float4 g = ((const float4*)gamma)[tid];
    __hip_bfloat16* o = out + (size_t)t * DIMD + tid * 4;
    o[0] = __float2bfloat16(v.x * sc * g.x);
    o[1] = __float2bfloat16(v.y * sc * g.y);
    o[2] = __float2bfloat16(v.z * sc * g.z);
    o[3] = __float2bfloat16(v.w * sc * g.w);
}

// 50-step coordinate descent per batch row, f64.
// es = exp(s) precomputed once -> iteration body is mul+min (no exp).
// a_1 = logk - log(n); then 49x: a <- logk + a - log( sum_n min(es_n * e^a, 1) )
__global__ void descent_kern(const double* __restrict__ s, double* __restrict__ a_out) {
    int r = blockIdx.x, tid = threadIdx.x;  // 1024 threads
    const double* sr = s + (size_t)r * NSEQ;
    double es[8];
    #pragma unroll
    for (int i = 0; i < 8; i++) es[i] = exp(sr[tid + i * 1024]);
    __shared__ double red[2][16];
    const double logk = log(1152.0);  // min(1024 * 9/8, 8192)
    double a = logk - log((double)NSEQ);
    for (int it = 1; it < NITERS; it++) {
        double ea = exp(a);
        double loc = 0.0;
        #pragma unroll
        for (int i = 0; i < 8; i++) {
            double p = es[i] * ea;
            loc += (p < 1.0 ? p : 1.0);
        }
        #pragma unroll
        for (int off = 32; off > 0; off >>= 1) loc += __shfl_down(loc, off);
        int pb = it & 1;
        if ((tid & 63) == 0) red[pb][tid >> 6] = loc;
        __syncthreads();
        double S = 0.0;
        #pragma unroll
        for (int i = 0; i < 16; i++) S += red[pb][i];
        a = logk + a - log(S);  // redundant per-thread; saves a 2nd barrier
    }
    if (tid == 0) a_out[r] = a;
}

// Selection per batch row (1 wave): all tokens with s+a>=0 (score==1.0 plateau,
// jax top_k tie-break = lowest index first), then fill by descending s.
__global__ void select_kern(const double* __restrict__ s, const double* __restrict__ a_arr,
                            int* __restrict__ sel) {
    int r = blockIdx.x, l = threadIdx.x;  // 64 threads
    const double* sr = s + (size_t)r * NSEQ;
    double a = a_arr[r];
    __shared__ double sw[NSEQ];  // 64 KB
    int cnt = 0;
    for (int base = 0; base < NSEQ; base += 64) {
        int idx = base + l;
        double v = sr[idx];
        bool sat = (v + a) >= 0.0;
        sw[idx] = sat ? -1.0e300 : v;
        unsigned long long m = __ballot(sat);
        int pre = __popcll(m & ((1ull << l) - 1ull));
        if (sat) {
            int slot = cnt + pre;
            if (slot < NHEAVY) sel[r * NHEAVY + slot] = r * NSEQ + idx;
        }
        cnt += (int)__popcll(m);
    }
    __syncthreads();
    for (int slot = cnt; slot < NHEAVY; slot++) {  // rarely taken fallback
        double best = -1.0e301; int bidx = NSEQ;
        for (int i = 0; i < NSEQ / 64; i++) {
            int idx = i * 64 + l;
            double v = sw[idx];
            if (v > best) { best = v; bidx = idx; }
        }
        #pragma unroll
        for (int off = 32; off > 0; off >>= 1) {
            double ov = __shfl_down(best, off);
            int oi = __shfl_down(bidx, off);
            if (ov > best || (ov == best && oi < bidx)) { best = ov; bidx = oi; }
        }
        bidx = __shfl(bidx, 0);
        if (l == 0) { sel[r * NHEAVY + slot] = r * NSEQ + bidx; sw[bidx] = -1.0e300; }
        __syncthreads();
    }
}

// C[M,N] = A[M,K] * Bt[N,K]^T, bf16 in / f32 acc. 128x128 tile, BK=64, 4 waves.
// gridDim.z = split-K factor (each z-slice does K/nz); bias added by bz==0 only.
// EPI 0: bf16 out = gelu(acc + bias)        (GEMM1; nz must be 1)
// EPI 1: f32  out = acc + bias              (light GEMM2; nz must be 1)
// EPI 2: atomicAdd(out[rows[m]], acc+bias)  (heavy GEMM2 scatter, split-K ok)
template <int EPI>
__global__ __launch_bounds__(256) void gemm_bt(
    const short* __restrict__ A, const short* __restrict__ Bt,
    const float* __restrict__ bias, float* __restrict__ outf,
    __hip_bfloat16* __restrict__ outb, const int* __restrict__ rows,
    int M, int N, int K) {
    __shared__ alignas(16) short As[128 * 64];
    __shared__ alignas(16) short Bs[128 * 64];
    // bijective XCD-aware swizzle on the flattened block id (m157/m204)
    int nx = gridDim.x, ny = gridDim.y;
    int nwg = nx * ny * gridDim.z;
    int id = ((int)blockIdx.z * ny + blockIdx.y) * nx + blockIdx.x;
    if ((nwg & 7) == 0) id = (id & 7) * (nwg >> 3) + (id >> 3);
    int bxi = id % nx; int rem = id / nx;
    int byi = rem % ny; int bz = rem / ny;
    int klen = K / (int)gridDim.z, k_start = bz * klen;

    int tid = threadIdx.x;
    int l = tid & 63, w = tid >> 6;
    int wr = w >> 1, wc = w & 1;
    int bn0 = bxi * 128, bm0 = byi * 128;

    f32x4 zero = {0.f, 0.f, 0.f, 0.f};
    f32x4 acc[4][4];
    #pragma unroll
    for (int i = 0; i < 4; i++)
        #pragma unroll
        for (int j = 0; j < 4; j++) acc[i][j] = zero;

    const int lrow = l & 15, lk = (l >> 4) * 8;
    int srow = tid >> 3, scol = (tid & 7) * 8;
    const short* Ag = A + (size_t)(bm0 + srow) * K + scol;
    const short* Bg = Bt + (size_t)(bn0 + srow) * K + scol;
    short* Asb = As + (tid & ~63) * 8;  // wave-uniform LDS base (+lane*16B by HW)
    short* Bsb = Bs + (tid & ~63) * 8;

    for (int k0 = k_start; k0 < k_start + klen; k0 += 64) {
        #pragma unroll
        for (int c = 0; c < 4; c++) {
            gload_lds16(Ag + (size_t)(c * 32) * K + k0, Asb + c * 2048);
            gload_lds16(Bg + (size_t)(c * 32) * K + k0, Bsb + c * 2048);
        }
        __syncthreads();  // compiler drains vmcnt before barrier
        #pragma unroll
        for (int kk = 0; kk < 2; kk++) {
            short8 af[4], bf[4];
            #pragma unroll
            for (int i = 0; i < 4; i++) {
                af[i] = *reinterpret_cast<const short8*>(&As[(wr * 64 + i * 16 + lrow) * 64 + kk * 32 + lk]);
                bf[i] = *reinterpret_cast<const short8*>(&Bs[(wc * 64 + i * 16 + lrow) * 64 + kk * 32 + lk]);
            }
            #pragma unroll
            for (int mi = 0; mi < 4; mi++)
                #pragma unroll
                for (int ni = 0; ni < 4; ni++)
                    acc[mi][ni] = __builtin_amdgcn_mfma_f32_16x16x32_bf16(af[mi], bf[ni], acc[mi][ni], 0, 0, 0);
        }
        __syncthreads();
    }

    bool addb = (bz == 0);
    int orow0 = bm0 + wr * 64, ocol0 = bn0 + wc * 64;
    #pragma unroll
    for (int mi = 0; mi < 4; mi++) {
        #pragma unroll
        for (int ni = 0; ni < 4; ni++) {
            int col = ocol0 + ni * 16 + (l & 15);
            float bv = addb ? bias[col] : 0.0f;
            #pragma unroll
            for (int rg = 0; rg < 4; rg++) {
                int row = orow0 + mi * 16 + (l >> 4) * 4 + rg;
                float v = acc[mi][ni][rg] + bv;
                if (EPI == 0) {
                    outb[(size_t)row * N + col] = __float2bfloat16(gelu_exact(v));
                } else if (EPI == 1) {
                    outf[(size_t)row * N + col] = v;
                } else {
                    unsafeAtomicAdd(outf + (size_t)rows[row] * DIMD + col, v);
                }
            }
        }
    }
}

extern "C" void kernel_launch(void* const* d_in, const int* in_sizes, int n_in,
                              void* d_out, int out_size, void* d_ws, size_t ws_size,
                              hipStream_t stream) {
    (void)in_sizes; (void)n_in; (void)out_size;
    const float* x      = (const float*)d_in[0];
    const float* rt     = (const float*)d_in[1];
    const float* lgamma = (const float*)d_in[2];
    const float* lw1    = (const float*)d_in[3];
    const float* lb1    = (const float*)d_in[4];
    const float* lw2    = (const float*)d_in[5];
    const float* lb2    = (const float*)d_in[6];
    const float* hgamma = (const float*)d_in[7];
    const float* hw1    = (const float*)d_in[8];
    const float* hb1    = (const float*)d_in[9];
    const float* hw2    = (const float*)d_in[10];
    const float* hb2    = (const float*)d_in[11];
    float* out = (float*)d_out;

    auto rnd = [](size_t b) { return (b + 255) & ~(size_t)255; };
    auto needed = [&](size_t ct) {
        size_t n = 0;
        n += rnd(NTOK * sizeof(double));            // s
        n += rnd(256);                              // a
        n += rnd(NSEL * sizeof(int));               // sel
        n += rnd((size_t)DLIGHT * DIMD * 2);        // wl1t
        n += rnd((size_t)DIMD * DLIGHT * 2);        // wl2t
        n += rnd((size_t)DHEAVY * DIMD * 2);        // wh1t
        n += rnd((size_t)DIMD * DHEAVY * 2);        // wh2t
        n += rnd((size_t)NSEL * DIMD * 2);          // xnh
        n += rnd((size_t)NSEL * DHEAVY * 2);        // hh
        n += rnd(ct * DIMD * 2);                    // xnc
        n += rnd(ct * DLIGHT * 2);                  // hlc
        return n;
    };
    size_t CT = 32768;
    while (CT > 2048 && needed(CT) > ws_size) CT >>= 1;

    char* base = (char*)d_ws;
    size_t off = 0;
    auto alloc = [&](size_t bytes) -> void* {
        void* p = base + off;
        off += rnd(bytes);
        return p;
    };
    double* s     = (double*)alloc(NTOK * sizeof(double));
    double* a_arr = (double*)alloc(256);
    int*    sel   = (int*)alloc(NSEL * sizeof(int));
    short*  wl1t  = (short*)alloc((size_t)DLIGHT * DIMD * 2);
    short*  wl2t  = (short*)alloc((size_t)DIMD * DLIGHT * 2);
    short*  wh1t  = (short*)alloc((size_t)DHEAVY * DIMD * 2);
    short*  wh2t  = (short*)alloc((size_t)DIMD * DHEAVY * 2);
    short*  xnh   = (short*)alloc((size_t)NSEL * DIMD * 2);
    short*  hh    = (short*)alloc((size_t)NSEL * DHEAVY * 2);
    short*  xnc   = (short*)alloc(CT * DIMD * 2);
    short*  hlc   = (short*)alloc(CT * DLIGHT * 2);

    // weights -> bf16, transposed to [N][K]
    cvt_transpose<<<dim3(DLIGHT / 32, DIMD / 32), dim3(32, 8), 0, stream>>>(lw1, (__hip_bfloat16*)wl1t, DIMD, DLIGHT);
    cvt_transpose<<<dim3(DIMD / 32, DLIGHT / 32), dim3(32, 8), 0, stream>>>(lw2, (__hip_bfloat16*)wl2t, DLIGHT, DIMD);
    cvt_transpose<<<dim3(DHEAVY / 32, DIMD / 32), dim3(32, 8), 0, stream>>>(hw1, (__hip_bfloat16*)wh1t, DIMD, DHEAVY);
    cvt_transpose<<<dim3(DIMD / 32, DHEAVY / 32), dim3(32, 8), 0, stream>>>(hw2, (__hip_bfloat16*)wh2t, DHEAVY, DIMD);

    // light path, chunked; router dot s is fused into the light rmsnorm pass
    for (size_t tok0 = 0; tok0 < NTOK; tok0 += CT) {
        rmsnorm_kern<false, true><<<(unsigned)CT, 256, 0, stream>>>(
            x, lgamma, nullptr, (__hip_bfloat16*)xnc, (int)tok0, rt, s);
        gemm_bt<0><<<dim3(DLIGHT / 128, (unsigned)(CT / 128)), 256, 0, stream>>>(
            xnc, wl1t, lb1, nullptr, (__hip_bfloat16*)hlc, nullptr, (int)CT, DLIGHT, DIMD);
        gemm_bt<1><<<dim3(DIMD / 128, (unsigned)(CT / 128)), 256, 0, stream>>>(
            hlc, wl2t, lb2, out + tok0 * DIMD, nullptr, nullptr, (int)CT, DIMD, DLIGHT);
    }

    // router
    descent_kern<<<NBATCH, 1024, 0, stream>>>(s, a_arr);
    select_kern<<<NBATCH, 64, 0, stream>>>(s, a_arr, sel);

    // heavy path: gather+rmsnorm, GEMM1 (+gelu), GEMM2 split-K scatter-add
    rmsnorm_kern<true, false><<<NSEL, 256, 0, stream>>>(
        x, hgamma, sel, (__hip_bfloat16*)xnh, 0, nullptr, nullptr);
    gemm_bt<0><<<dim3(DHEAVY / 128, NSEL / 128), 256, 0, stream>>>(
        xnh, wh1t, hb1, nullptr, (__hip_bfloat16*)hh, nullptr, NSEL, DHEAVY, DIMD);
    gemm_bt<2><<<dim3(DIMD / 128, NSEL / 128, 4), 256, 0, stream>>>(
        hh, wh2t, hb2, out, nullptr, sel, NSEL, DIMD, DHEAVY);
}

// Round 6
// 467.350 us; speedup vs baseline: 1.0656x; 1.0656x over previous
//
#include <hip/hip_runtime.h>
#include <hip/hip_bf16.h>
#include <math.h>

#define DIMD   1024
#define NBATCH 4
#define NSEQ   8192
#define NTOK   (NBATCH * NSEQ)
#define NHEAVY 1024
#define NSEL   (NBATCH * NHEAVY)
#define DLIGHT 512
#define DHEAVY 4096
#define NITERS 50
#define SPLITK 4

typedef __attribute__((ext_vector_type(8))) short short8;
typedef __attribute__((ext_vector_type(4))) float f32x4;

__device__ __forceinline__ float gelu_exact(float x) {
    return 0.5f * x * (1.0f + erff(x * 0.7071067811865475f));
}

__device__ __forceinline__ void gload_lds16(const void* g, void* l) {
    __builtin_amdgcn_global_load_lds(
        (const __attribute__((address_space(1))) void*)g,
        (__attribute__((address_space(3))) void*)l,
        16, 0, 0);
}

// in[K][N] f32  ->  out[N][K] bf16   (transpose + convert)
__global__ void cvt_transpose(const float* __restrict__ in, __hip_bfloat16* __restrict__ out,
                              int K, int N) {
    __shared__ float tile[32][33];
    int n0 = blockIdx.x * 32, k0 = blockIdx.y * 32;
    int tx = threadIdx.x, ty = threadIdx.y;  // (32, 8)
    #pragma unroll
    for (int j = 0; j < 4; j++)
        tile[ty + 8 * j][tx] = in[(size_t)(k0 + ty + 8 * j) * N + (n0 + tx)];
    __syncthreads();
    #pragma unroll
    for (int j = 0; j < 4; j++)
        out[(size_t)(n0 + ty + 8 * j) * K + (k0 + tx)] = __float2bfloat16(tile[tx][ty + 8 * j]);
}

// rmsnorm (fp32) -> bf16. GATHER: token row from sel list.
// WITH_S: also computes s[token] = dot(x_row, rt) in f64 (fused router dot).
template <bool GATHER, bool WITH_S>
__global__ void rmsnorm_kern(const float* __restrict__ x, const float* __restrict__ gamma,
                             const int* __restrict__ rows, __hip_bfloat16* __restrict__ out,
                             int tok0, const float* __restrict__ rt, double* __restrict__ s_out) {
    int t = blockIdx.x;
    int grow = GATHER ? rows[t] : (tok0 + t);
    const float4* xr = (const float4*)(x + (size_t)grow * DIMD);
    int tid = threadIdx.x;  // 256
    float4 v = xr[tid];
    float ss = v.x * v.x + v.y * v.y + v.z * v.z + v.w * v.w;
    double sd = 0.0;
    if (WITH_S) {
        float4 rv = ((const float4*)rt)[tid];
        sd = (double)v.x * rv.x + (double)v.y * rv.y + (double)v.z * rv.z + (double)v.w * rv.w;
    }
    #pragma unroll
    for (int off = 32; off > 0; off >>= 1) {
        ss += __shfl_down(ss, off);
        if (WITH_S) sd += __shfl_down(sd, off);
    }
    __shared__ float red[4];
    __shared__ double redd[4];
    if ((tid & 63) == 0) { red[tid >> 6] = ss; if (WITH_S) redd[tid >> 6] = sd; }
    __syncthreads();
    float tot = red[0] + red[1] + red[2] + red[3];
    if (WITH_S && tid == 0) s_out[grow] = redd[0] + redd[1] + redd[2] + redd[3];
    float sc = 32.0f / fmaxf(sqrtf(tot), 1e-12f);  // sqrt(1024)=32
    float4 g = ((const float4*)gamma)[tid];
    __hip_bfloat16* o = out + (size_t)t * DIMD + tid * 4;
    o[0] = __float2bfloat16(v.x * sc * g.x);
    o[1] = __float2bfloat16(v.y * sc * g.y);
    o[2] = __float2bfloat16(v.z * sc * g.z);
    o[3] = __float2bfloat16(v.w * sc * g.w);
}

// 50-step coordinate descent per batch row, f64.
// es = exp(s) precomputed once -> iteration body is mul+min (no exp).
// a_1 = logk - log(n); then 49x: a <- logk + a - log( sum_n min(es_n * e^a, 1) )
__global__ void descent_kern(const double* __restrict__ s, double* __restrict__ a_out) {
    int r = blockIdx.x, tid = threadIdx.x;  // 1024 threads
    const double* sr = s + (size_t)r * NSEQ;
    double es[8];
    #pragma unroll
    for (int i = 0; i < 8; i++) es[i] = exp(sr[tid + i * 1024]);
    __shared__ double red[2][16];
    const double logk = log(1152.0);  // min(1024 * 9/8, 8192)
    double a = logk - log((double)NSEQ);
    for (int it = 1; it < NITERS; it++) {
        double ea = exp(a);
        double loc = 0.0;
        #pragma unroll
        for (int i = 0; i < 8; i++) {
            double p = es[i] * ea;
            loc += (p < 1.0 ? p : 1.0);
        }
        #pragma unroll
        for (int off = 32; off > 0; off >>= 1) loc += __shfl_down(loc, off);
        int pb = it & 1;
        if ((tid & 63) == 0) red[pb][tid >> 6] = loc;
        __syncthreads();
        double S = 0.0;
        #pragma unroll
        for (int i = 0; i < 16; i++) S += red[pb][i];
        a = logk + a - log(S);  // redundant per-thread; saves a 2nd barrier
    }
    if (tid == 0) a_out[r] = a;
}

// Selection per batch row (1 wave): all tokens with s+a>=0 (score==1.0 plateau,
// jax top_k tie-break = lowest index first), then fill by descending s.
__global__ void select_kern(const double* __restrict__ s, const double* __restrict__ a_arr,
                            int* __restrict__ sel) {
    int r = blockIdx.x, l = threadIdx.x;  // 64 threads
    const double* sr = s + (size_t)r * NSEQ;
    double a = a_arr[r];
    __shared__ double sw[NSEQ];  // 64 KB
    int cnt = 0;
    for (int base = 0; base < NSEQ; base += 64) {
        int idx = base + l;
        double v = sr[idx];
        bool sat = (v + a) >= 0.0;
        sw[idx] = sat ? -1.0e300 : v;
        unsigned long long m = __ballot(sat);
        int pre = __popcll(m & ((1ull << l) - 1ull));
        if (sat) {
            int slot = cnt + pre;
            if (slot < NHEAVY) sel[r * NHEAVY + slot] = r * NSEQ + idx;
        }
        cnt += (int)__popcll(m);
    }
    __syncthreads();
    for (int slot = cnt; slot < NHEAVY; slot++) {  // rarely taken fallback
        double best = -1.0e301; int bidx = NSEQ;
        for (int i = 0; i < NSEQ / 64; i++) {
            int idx = i * 64 + l;
            double v = sw[idx];
            if (v > best) { best = v; bidx = idx; }
        }
        #pragma unroll
        for (int off = 32; off > 0; off >>= 1) {
            double ov = __shfl_down(best, off);
            int oi = __shfl_down(bidx, off);
            if (ov > best || (ov == best && oi < bidx)) { best = ov; bidx = oi; }
        }
        bidx = __shfl(bidx, 0);
        if (l == 0) { sel[r * NHEAVY + slot] = r * NSEQ + bidx; sw[bidx] = -1.0e300; }
        __syncthreads();
    }
}

// C[M,N] = A[M,K] * Bt[N,K]^T, bf16 in / f32 acc. 128x128 tile, BK=64, 4 waves.
// gridDim.z = split-K factor (each z-slice does K/nz).
// EPI 0: bf16 out = gelu(acc + bias)            (GEMM1; nz must be 1)
// EPI 1: f32  out = acc + bias                  (light GEMM2; nz must be 1)
// EPI 2: f32  partial[bz][m][n] = acc (no bias) (heavy GEMM2, atomic-free split-K)
template <int EPI>
__global__ __launch_bounds__(256) void gemm_bt(
    const short* __restrict__ A, const short* __restrict__ Bt,
    const float* __restrict__ bias, float* __restrict__ outf,
    __hip_bfloat16* __restrict__ outb,
    int M, int N, int K) {
    __shared__ alignas(16) short As[128 * 64];
    __shared__ alignas(16) short Bs[128 * 64];
    // bijective XCD-aware swizzle on the flattened block id (m157/m204)
    int nx = gridDim.x, ny = gridDim.y;
    int nwg = nx * ny * gridDim.z;
    int id = ((int)blockIdx.z * ny + blockIdx.y) * nx + blockIdx.x;
    if ((nwg & 7) == 0) id = (id & 7) * (nwg >> 3) + (id >> 3);
    int bxi = id % nx; int rem = id / nx;
    int byi = rem % ny; int bz = rem / ny;
    int klen = K / (int)gridDim.z, k_start = bz * klen;

    int tid = threadIdx.x;
    int l = tid & 63, w = tid >> 6;
    int wr = w >> 1, wc = w & 1;
    int bn0 = bxi * 128, bm0 = byi * 128;

    f32x4 zero = {0.f, 0.f, 0.f, 0.f};
    f32x4 acc[4][4];
    #pragma unroll
    for (int i = 0; i < 4; i++)
        #pragma unroll
        for (int j = 0; j < 4; j++) acc[i][j] = zero;

    const int lrow = l & 15, lk = (l >> 4) * 8;
    int srow = tid >> 3, scol = (tid & 7) * 8;
    const short* Ag = A + (size_t)(bm0 + srow) * K + scol;
    const short* Bg = Bt + (size_t)(bn0 + srow) * K + scol;
    short* Asb = As + (tid & ~63) * 8;  // wave-uniform LDS base (+lane*16B by HW)
    short* Bsb = Bs + (tid & ~63) * 8;

    for (int k0 = k_start; k0 < k_start + klen; k0 += 64) {
        #pragma unroll
        for (int c = 0; c < 4; c++) {
            gload_lds16(Ag + (size_t)(c * 32) * K + k0, Asb + c * 2048);
            gload_lds16(Bg + (size_t)(c * 32) * K + k0, Bsb + c * 2048);
        }
        __syncthreads();  // compiler drains vmcnt before barrier
        #pragma unroll
        for (int kk = 0; kk < 2; kk++) {
            short8 af[4], bf[4];
            #pragma unroll
            for (int i = 0; i < 4; i++) {
                af[i] = *reinterpret_cast<const short8*>(&As[(wr * 64 + i * 16 + lrow) * 64 + kk * 32 + lk]);
                bf[i] = *reinterpret_cast<const short8*>(&Bs[(wc * 64 + i * 16 + lrow) * 64 + kk * 32 + lk]);
            }
            #pragma unroll
            for (int mi = 0; mi < 4; mi++)
                #pragma unroll
                for (int ni = 0; ni < 4; ni++)
                    acc[mi][ni] = __builtin_amdgcn_mfma_f32_16x16x32_bf16(af[mi], bf[ni], acc[mi][ni], 0, 0, 0);
        }
        __syncthreads();
    }

    int orow0 = bm0 + wr * 64, ocol0 = bn0 + wc * 64;
    #pragma unroll
    for (int mi = 0; mi < 4; mi++) {
        #pragma unroll
        for (int ni = 0; ni < 4; ni++) {
            int col = ocol0 + ni * 16 + (l & 15);
            float bv = (EPI == 2) ? 0.0f : bias[col];
            #pragma unroll
            for (int rg = 0; rg < 4; rg++) {
                int row = orow0 + mi * 16 + (l >> 4) * 4 + rg;
                float v = acc[mi][ni][rg] + bv;
                if (EPI == 0) {
                    outb[(size_t)row * N + col] = __float2bfloat16(gelu_exact(v));
                } else if (EPI == 1) {
                    outf[(size_t)row * N + col] = v;
                } else {
                    outf[((size_t)bz * M + row) * (size_t)N + col] = v;
                }
            }
        }
    }
}

// sum SPLITK partials + bias, non-atomic RMW scatter into out[sel[h]].
// one block per heavy row; each (row,col) owned by exactly one thread.
__global__ __launch_bounds__(256) void reduce_scatter_kern(
    const float* __restrict__ P, const float* __restrict__ bias,
    const int* __restrict__ sel, float* __restrict__ out) {
    int h = blockIdx.x;          // 0..NSEL-1
    int tid = threadIdx.x;       // 256
    int grow = sel[h];
    const float4* p = (const float4*)(P + (size_t)h * DIMD);
    const size_t stride = (size_t)NSEL * DIMD / 4;
    float4 a = p[tid];
    float4 b = p[tid + stride];
    float4 c = p[tid + 2 * stride];
    float4 d = p[tid + 3 * stride];
    float4 bv = ((const float4*)bias)[tid];
    float4* o = (float4*)(out + (size_t)grow * DIMD);
    float4 ov = o[tid];
    ov.x += a.x + b.x + c.x + d.x + bv.x;
    ov.y += a.y + b.y + c.y + d.y + bv.y;
    ov.z += a.z + b.z + c.z + d.z + bv.z;
    ov.w += a.w + b.w + c.w + d.w + bv.w;
    o[tid] = ov;
}

extern "C" void kernel_launch(void* const* d_in, const int* in_sizes, int n_in,
                              void* d_out, int out_size, void* d_ws, size_t ws_size,
                              hipStream_t stream) {
    (void)in_sizes; (void)n_in; (void)out_size;
    const float* x      = (const float*)d_in[0];
    const float* rt     = (const float*)d_in[1];
    const float* lgamma = (const float*)d_in[2];
    const float* lw1    = (const float*)d_in[3];
    const float* lb1    = (const float*)d_in[4];
    const float* lw2    = (const float*)d_in[5];
    const float* lb2    = (const float*)d_in[6];
    const float* hgamma = (const float*)d_in[7];
    const float* hw1    = (const float*)d_in[8];
    const float* hb1    = (const float*)d_in[9];
    const float* hw2    = (const float*)d_in[10];
    const float* hb2    = (const float*)d_in[11];
    float* out = (float*)d_out;

    auto rnd = [](size_t b) { return (b + 255) & ~(size_t)255; };
    auto needed = [&](size_t ct) {
        size_t n = 0;
        n += rnd(NTOK * sizeof(double));                      // s
        n += rnd(256);                                        // a
        n += rnd(NSEL * sizeof(int));                         // sel
        n += rnd((size_t)DLIGHT * DIMD * 2);                  // wl1t
        n += rnd((size_t)DIMD * DLIGHT * 2);                  // wl2t
        n += rnd((size_t)DHEAVY * DIMD * 2);                  // wh1t
        n += rnd((size_t)DIMD * DHEAVY * 2);                  // wh2t
        n += rnd((size_t)NSEL * DIMD * 2);                    // xnh
        n += rnd((size_t)NSEL * DHEAVY * 2);                  // hh
        n += rnd((size_t)SPLITK * NSEL * DIMD * sizeof(float)); // pheavy
        n += rnd(ct * DIMD * 2);                              // xnc
        n += rnd(ct * DLIGHT * 2);                            // hlc
        return n;
    };
    size_t CT = 32768;
    while (CT > 2048 && needed(CT) > ws_size) CT >>= 1;

    char* base = (char*)d_ws;
    size_t off = 0;
    auto alloc = [&](size_t bytes) -> void* {
        void* p = base + off;
        off += rnd(bytes);
        return p;
    };
    double* s     = (double*)alloc(NTOK * sizeof(double));
    double* a_arr = (double*)alloc(256);
    int*    sel   = (int*)alloc(NSEL * sizeof(int));
    short*  wl1t  = (short*)alloc((size_t)DLIGHT * DIMD * 2);
    short*  wl2t  = (short*)alloc((size_t)DIMD * DLIGHT * 2);
    short*  wh1t  = (short*)alloc((size_t)DHEAVY * DIMD * 2);
    short*  wh2t  = (short*)alloc((size_t)DIMD * DHEAVY * 2);
    short*  xnh   = (short*)alloc((size_t)NSEL * DIMD * 2);
    short*  hh    = (short*)alloc((size_t)NSEL * DHEAVY * 2);
    float*  ph    = (float*)alloc((size_t)SPLITK * NSEL * DIMD * sizeof(float));
    short*  xnc   = (short*)alloc(CT * DIMD * 2);
    short*  hlc   = (short*)alloc(CT * DLIGHT * 2);

    // weights -> bf16, transposed to [N][K]
    cvt_transpose<<<dim3(DLIGHT / 32, DIMD / 32), dim3(32, 8), 0, stream>>>(lw1, (__hip_bfloat16*)wl1t, DIMD, DLIGHT);
    cvt_transpose<<<dim3(DIMD / 32, DLIGHT / 32), dim3(32, 8), 0, stream>>>(lw2, (__hip_bfloat16*)wl2t, DLIGHT, DIMD);
    cvt_transpose<<<dim3(DHEAVY / 32, DIMD / 32), dim3(32, 8), 0, stream>>>(hw1, (__hip_bfloat16*)wh1t, DIMD, DHEAVY);
    cvt_transpose<<<dim3(DIMD / 32, DHEAVY / 32), dim3(32, 8), 0, stream>>>(hw2, (__hip_bfloat16*)wh2t, DHEAVY, DIMD);

    // light path, chunked; router dot s is fused into the light rmsnorm pass
    for (size_t tok0 = 0; tok0 < NTOK; tok0 += CT) {
        rmsnorm_kern<false, true><<<(unsigned)CT, 256, 0, stream>>>(
            x, lgamma, nullptr, (__hip_bfloat16*)xnc, (int)tok0, rt, s);
        gemm_bt<0><<<dim3(DLIGHT / 128, (unsigned)(CT / 128)), 256, 0, stream>>>(
            xnc, wl1t, lb1, nullptr, (__hip_bfloat16*)hlc, (int)CT, DLIGHT, DIMD);
        gemm_bt<1><<<dim3(DIMD / 128, (unsigned)(CT / 128)), 256, 0, stream>>>(
            hlc, wl2t, lb2, out + tok0 * DIMD, nullptr, (int)CT, DIMD, DLIGHT);
    }

    // router
    descent_kern<<<NBATCH, 1024, 0, stream>>>(s, a_arr);
    select_kern<<<NBATCH, 64, 0, stream>>>(s, a_arr, sel);

    // heavy path: gather+rmsnorm, GEMM1 (+gelu), GEMM2 split-K partials, reduce+scatter
    rmsnorm_kern<true, false><<<NSEL, 256, 0, stream>>>(
        x, hgamma, sel, (__hip_bfloat16*)xnh, 0, nullptr, nullptr);
    gemm_bt<0><<<dim3(DHEAVY / 128, NSEL / 128), 256, 0, stream>>>(
        xnh, wh1t, hb1, nullptr, (__hip_bfloat16*)hh, NSEL, DHEAVY, DIMD);
    gemm_bt<2><<<dim3(DIMD / 128, NSEL / 128, SPLITK), 256, 0, stream>>>(
        hh, wh2t, nullptr, ph, nullptr, NSEL, DIMD, DHEAVY);
    reduce_scatter_kern<<<NSEL, 256, 0, stream>>>(ph, hb2, sel, out);
}